// Round 1
// baseline (1209.709 us; speedup 1.0000x reference)
//
#include <hip/hip_runtime.h>
#include <hip/hip_bf16.h>
#include <math.h>

typedef __attribute__((ext_vector_type(8))) short bf16x8;
typedef __attribute__((ext_vector_type(4))) float f32x4;

#define N_TOK 1024
#define HID   2048
#define NEXP  16
#define INTER 1024
#define TOPK  6
#define CAP   1024

__device__ __forceinline__ unsigned short f2bf(float f) {
  unsigned u = __builtin_bit_cast(unsigned, f);
  u += 0x7fffu + ((u >> 16) & 1u);          // round-to-nearest-even
  return (unsigned short)(u >> 16);
}

// ---------------------------------------------------------------- router ----
// One block per token: logits (4 waves x 4 experts each), sigmoid scoring,
// grouped top-k (noaux_tc), renorm*2.5, atomic slot dispatch. Also x -> bf16.
__global__ __launch_bounds__(256) void router_k(
    const float* __restrict__ x, const float* __restrict__ gw,
    const float* __restrict__ gb, int* __restrict__ counts,
    int* __restrict__ tok_list, float* __restrict__ pw,
    unsigned short* __restrict__ x_bf)
{
  const int t   = blockIdx.x;
  const int tid = threadIdx.x;
  __shared__ float xrow[HID];
  __shared__ float logits[NEXP];

  for (int i = tid; i < HID; i += 256) {
    float v = x[(size_t)t * HID + i];
    xrow[i] = v;
    x_bf[(size_t)t * HID + i] = f2bf(v);
  }
  __syncthreads();

  const int w = tid >> 6, lane = tid & 63;
  for (int s = 0; s < 4; ++s) {
    int e = w * 4 + s;
    const float* g = gw + (size_t)e * HID;
    float p = 0.f;
    for (int i = lane; i < HID; i += 64) p += xrow[i] * g[i];
    for (int off = 32; off; off >>= 1) p += __shfl_down(p, off);
    if (lane == 0) logits[e] = p;
  }
  __syncthreads();

  if (tid == 0) {
    float sc[NEXP], scorr[NEXP];
    for (int e = 0; e < NEXP; ++e) {
      float s1 = 1.f / (1.f + expf(-logits[e]));
      sc[e] = s1; scorr[e] = s1 + gb[e];
    }
    float gs[4];
    for (int g = 0; g < 4; ++g) {            // top-2 sum within group of 4
      float m1 = -1e30f, m2 = -1e30f;
      for (int j = 0; j < 4; ++j) {
        float v = scorr[g * 4 + j];
        if (v > m1) { m2 = m1; m1 = v; } else if (v > m2) m2 = v;
      }
      gs[g] = m1 + m2;
    }
    int g1 = 0;
    for (int g = 1; g < 4; ++g) if (gs[g] > gs[g1]) g1 = g;
    int g2 = -1;
    for (int g = 0; g < 4; ++g) { if (g == g1) continue; if (g2 < 0 || gs[g] > gs[g2]) g2 = g; }

    bool taken[NEXP];
    for (int e = 0; e < NEXP; ++e) taken[e] = false;
    int ids[TOPK]; float wv[TOPK]; float wsum = 0.f;
    for (int k = 0; k < TOPK; ++k) {
      int best = -1; float bv = -1e30f;
      for (int e = 0; e < NEXP; ++e) {
        int grp = e >> 2;
        if (grp != g1 && grp != g2) continue;
        if (taken[e]) continue;
        if (scorr[e] > bv) { bv = scorr[e]; best = e; }
      }
      taken[best] = true; ids[k] = best; wv[k] = sc[best]; wsum += sc[best];
    }
    float inv = 2.5f / wsum;
    for (int k = 0; k < TOPK; ++k) {
      int e = ids[k];
      int slot = atomicAdd(&counts[e], 1);
      tok_list[e * CAP + slot] = t;
      pw[e * CAP + slot] = wv[k] * inv;
    }
  }
}

// ------------------------------------------------------------------ GEMM ----
// Tile: BM=64, BN=64 (MODE0: g-cols + matching u-cols) or 128, BK=64.
// A (bf16, row-major along K) staged as [64][64]; B (f32 [K][N]) staged
// TRANSPOSED+converted as [n][k] bf16 so both frag reads are ds_read_b128.
// XOR swizzle byte^=((row&7)<<4) on all LDS writes/reads (G4).
// MODE 0: swiglu epilogue -> bf16 act.  MODE 1: y*pw atomic scatter-add.
// MODE 2: plain f32 store.
template<int MODE>
__global__ __launch_bounds__(256) void gemm_k(
    const unsigned short* __restrict__ A, int lda, size_t a_estride,
    const float* __restrict__ W, int K, int Nfull, size_t w_estride,
    const int* __restrict__ counts, int M_direct,
    const int* __restrict__ tok_list,
    unsigned short* __restrict__ act_out, int act_ld, size_t act_estride, int u_off,
    const float* __restrict__ pw, float* __restrict__ out, int out_ld)
{
  const int e  = blockIdx.z;
  const int m0 = blockIdx.y * 64;
  const int M  = counts ? counts[e] : M_direct;
  if (m0 >= M) return;
  const int BN = (MODE == 0) ? 64 : 128;
  const int n0 = blockIdx.x * BN;

  __shared__ __align__(16) unsigned short Al[64 * 64];    // 8 KB
  __shared__ __align__(16) unsigned short Bl[128 * 64];   // 16 KB

  const int tid  = threadIdx.x;
  const int lane = tid & 63;
  const int wid  = tid >> 6;
  const int wm = wid >> 1, wn = wid & 1;
  const int l15 = lane & 15;

  const float* Wp = W + (size_t)e * w_estride;
  const unsigned short* Ap = A + (size_t)e * a_estride;

  // ---- A staging plan: 2 chunks of 16B per thread ----
  const unsigned short* aptr[2]; int aoff[2];
  #pragma unroll
  for (int i = 0; i < 2; ++i) {
    int c = tid + 256 * i;          // 0..511
    int r = c >> 3, col = (c & 7) * 8;
    int slot = m0 + r;
    const unsigned short* p = nullptr;
    if (slot < M) {
      int row_idx = (MODE == 0 && tok_list) ? tok_list[e * CAP + slot] : slot;
      p = Ap + (size_t)row_idx * lda + col;
    }
    aptr[i] = p;
    aoff[i] = (r * 128 + col * 2) ^ ((r & 7) << 4);
  }
  // ---- B staging plan: 8 float4 chunks per thread ----
  int bk_[8], bnl_[8]; size_t bgoff[8];
  #pragma unroll
  for (int i = 0; i < 8; ++i) {
    int c = tid + 256 * i;          // 0..2047
    int k = c >> 5, nl = (c & 31) * 4;
    bk_[i] = k; bnl_[i] = nl;
    int ng;
    if (MODE == 0) ng = (nl < 64) ? (n0 + nl) : (u_off + n0 + nl - 64);
    else           ng = n0 + nl;
    bgoff[i] = (size_t)k * Nfull + ng;
  }

  int bn[4];
  if (MODE == 0) { bn[0] = wn*32; bn[1] = wn*32+16; bn[2] = 64+wn*32; bn[3] = 80+wn*32; }
  else           { bn[0] = wn*64; bn[1] = wn*64+16; bn[2] = wn*64+32; bn[3] = wn*64+48; }

  f32x4 acc[2][4];
  #pragma unroll
  for (int a0 = 0; a0 < 2; ++a0)
    #pragma unroll
    for (int b0 = 0; b0 < 4; ++b0) acc[a0][b0] = (f32x4){0.f, 0.f, 0.f, 0.f};

  for (int kt = 0; kt < K; kt += 64) {
    // stage A (bf16 copy)
    #pragma unroll
    for (int i = 0; i < 2; ++i) {
      uint4 v = {0u, 0u, 0u, 0u};
      if (aptr[i]) v = *(const uint4*)(aptr[i] + kt);
      *(uint4*)((char*)Al + aoff[i]) = v;
    }
    // stage B (f32 -> bf16, transpose into [n][k])
    #pragma unroll
    for (int i = 0; i < 8; ++i) {
      float4 f = *(const float4*)(Wp + (size_t)kt * Nfull + bgoff[i]);
      unsigned short h[4] = { f2bf(f.x), f2bf(f.y), f2bf(f.z), f2bf(f.w) };
      #pragma unroll
      for (int j = 0; j < 4; ++j) {
        int r2 = bnl_[i] + j;
        int off = (r2 * 128 + bk_[i] * 2) ^ ((r2 & 7) << 4);
        *(unsigned short*)((char*)Bl + off) = h[j];
      }
    }
    __syncthreads();

    #pragma unroll
    for (int kk = 0; kk < 64; kk += 32) {
      bf16x8 af[2], bfv[4];
      #pragma unroll
      for (int mi = 0; mi < 2; ++mi) {
        int r = wm * 32 + mi * 16 + l15;
        int off = (r * 128 + (kk + ((lane >> 4) << 3)) * 2) ^ ((r & 7) << 4);
        af[mi] = *(const bf16x8*)((const char*)Al + off);
      }
      #pragma unroll
      for (int bj = 0; bj < 4; ++bj) {
        int r = bn[bj] + l15;
        int off = (r * 128 + (kk + ((lane >> 4) << 3)) * 2) ^ ((r & 7) << 4);
        bfv[bj] = *(const bf16x8*)((const char*)Bl + off);
      }
      #pragma unroll
      for (int mi = 0; mi < 2; ++mi)
        #pragma unroll
        for (int bj = 0; bj < 4; ++bj)
          acc[mi][bj] = __builtin_amdgcn_mfma_f32_16x16x32_bf16(af[mi], bfv[bj], acc[mi][bj], 0, 0, 0);
    }
    __syncthreads();
  }

  // ---- epilogue ----  C/D: col=lane&15, row=(lane>>4)*4+reg
  const int rowin = (lane >> 4) * 4;
  if (MODE == 0) {
    #pragma unroll
    for (int mi = 0; mi < 2; ++mi)
      #pragma unroll
      for (int r = 0; r < 4; ++r) {
        int slot = m0 + wm * 32 + mi * 16 + rowin + r;
        if (slot >= M) continue;
        #pragma unroll
        for (int bjh = 0; bjh < 2; ++bjh) {
          float g = acc[mi][bjh][r];
          float u = acc[mi][bjh + 2][r];
          float sv = g / (1.f + expf(-g)) * u;     // silu(g)*u
          int colc = n0 + bn[bjh] + l15;
          act_out[(size_t)e * act_estride + (size_t)slot * act_ld + colc] = f2bf(sv);
        }
      }
  } else if (MODE == 1) {
    #pragma unroll
    for (int mi = 0; mi < 2; ++mi)
      #pragma unroll
      for (int r = 0; r < 4; ++r) {
        int slot = m0 + wm * 32 + mi * 16 + rowin + r;
        if (slot >= M) continue;
        int tokn = tok_list[e * CAP + slot];
        float wvv = pw[e * CAP + slot];
        float* orow = out + (size_t)tokn * out_ld;
        #pragma unroll
        for (int bj = 0; bj < 4; ++bj)
          atomicAdd(orow + (n0 + bn[bj] + l15), acc[mi][bj][r] * wvv);
      }
  } else {
    #pragma unroll
    for (int mi = 0; mi < 2; ++mi)
      #pragma unroll
      for (int r = 0; r < 4; ++r) {
        int rowg = m0 + wm * 32 + mi * 16 + rowin + r;
        #pragma unroll
        for (int bj = 0; bj < 4; ++bj)
          out[(size_t)rowg * out_ld + (n0 + bn[bj] + l15)] = acc[mi][bj][r];
      }
  }
}

// --------------------------------------------------------------- launcher ---
extern "C" void kernel_launch(void* const* d_in, const int* in_sizes, int n_in,
                              void* d_out, int out_size, void* d_ws, size_t ws_size,
                              hipStream_t stream) {
  const float* x   = (const float*)d_in[0];
  const float* gw  = (const float*)d_in[1];
  const float* gb  = (const float*)d_in[2];
  const float* wgu = (const float*)d_in[3];
  const float* wd  = (const float*)d_in[4];
  const float* sgu = (const float*)d_in[5];
  const float* sd  = (const float*)d_in[6];
  float* out = (float*)d_out;

  char* ws = (char*)d_ws;
  int*   counts   = (int*)ws;                                   // 256 B
  int*   tok_list = (int*)(ws + 256);                           // 64 KB
  float* pw       = (float*)(ws + 256 + (size_t)64 * 1024);     // 64 KB
  unsigned short* x_bf   = (unsigned short*)(ws + 256 + (size_t)128 * 1024);
  unsigned short* act_e  = x_bf + (size_t)N_TOK * HID;          // 16*1024*1024 bf16
  unsigned short* act_sh = act_e + (size_t)NEXP * CAP * INTER;  // 1024*2048 bf16

  hipMemsetAsync(counts, 0, 256, stream);
  router_k<<<N_TOK, 256, 0, stream>>>(x, gw, gb, counts, tok_list, pw, x_bf);

  // shared gemm1: x[1024,2048] @ sgu[2048,4096], swiglu -> act_sh[1024,2048]
  gemm_k<0><<<dim3(32, 16, 1), 256, 0, stream>>>(
      x_bf, HID, 0, sgu, HID, 4096, 0, nullptr, N_TOK, nullptr,
      act_sh, 2048, 0, 2048, nullptr, nullptr, 0);

  // expert gemm1: gather(x)[cnt,2048] @ wgu[e][2048,2048], swiglu -> act_e[e][*,1024]
  gemm_k<0><<<dim3(16, 16, 16), 256, 0, stream>>>(
      x_bf, HID, 0, wgu, HID, 2 * INTER, (size_t)HID * 2 * INTER, counts, 0, tok_list,
      act_e, INTER, (size_t)CAP * INTER, INTER, nullptr, nullptr, 0);

  // shared gemm2: act_sh[1024,2048] @ sd[2048,2048] -> out (plain store, inits d_out)
  gemm_k<2><<<dim3(16, 16, 1), 256, 0, stream>>>(
      act_sh, 2048, 0, sd, 2048, HID, 0, nullptr, N_TOK, nullptr,
      nullptr, 0, 0, 0, nullptr, out, HID);

  // expert gemm2: act_e[e][cnt,1024] @ wd[e][1024,2048] * pw -> atomicAdd(out)
  gemm_k<1><<<dim3(16, 16, 16), 256, 0, stream>>>(
      act_e, INTER, (size_t)CAP * INTER, wd, INTER, HID, (size_t)INTER * HID, counts, 0, tok_list,
      nullptr, 0, 0, 0, pw, out, HID);
}

// Round 2
// 531.936 us; speedup vs baseline: 2.2742x; 2.2742x over previous
//
#include <hip/hip_runtime.h>
#include <hip/hip_bf16.h>
#include <math.h>

typedef __attribute__((ext_vector_type(8))) short bf16x8;
typedef __attribute__((ext_vector_type(4))) float f32x4;

#define N_TOK 1024
#define HID   2048
#define NEXP  16
#define INTER 1024
#define TOPK  6
#define CAP   1024

__device__ __forceinline__ unsigned short f2bf(float f) {
  unsigned u = __builtin_bit_cast(unsigned, f);
  u += 0x7fffu + ((u >> 16) & 1u);          // round-to-nearest-even
  return (unsigned short)(u >> 16);
}

__device__ __forceinline__ void gll16(const void* g, void* l) {
  __builtin_amdgcn_global_load_lds(
      (const __attribute__((address_space(1))) unsigned int*)g,
      (__attribute__((address_space(3))) unsigned int*)l, 16, 0, 0);
}

// ---------------------------------------------------------------- router ----
__global__ __launch_bounds__(256) void router_k(
    const float* __restrict__ x, const float* __restrict__ gw,
    const float* __restrict__ gb, int* __restrict__ counts,
    int* __restrict__ tok_list, float* __restrict__ pw,
    unsigned short* __restrict__ x_bf)
{
  const int t   = blockIdx.x;
  const int tid = threadIdx.x;
  __shared__ float xrow[HID];
  __shared__ float logits[NEXP];

  for (int i = tid; i < HID; i += 256) {
    float v = x[(size_t)t * HID + i];
    xrow[i] = v;
    x_bf[(size_t)t * HID + i] = f2bf(v);
  }
  __syncthreads();

  const int w = tid >> 6, lane = tid & 63;
  for (int s = 0; s < 4; ++s) {
    int e = w * 4 + s;
    const float* g = gw + (size_t)e * HID;
    float p = 0.f;
    for (int i = lane; i < HID; i += 64) p += xrow[i] * g[i];
    for (int off = 32; off; off >>= 1) p += __shfl_down(p, off);
    if (lane == 0) logits[e] = p;
  }
  __syncthreads();

  if (tid == 0) {
    float sc[NEXP], scorr[NEXP];
    for (int e = 0; e < NEXP; ++e) {
      float s1 = 1.f / (1.f + expf(-logits[e]));
      sc[e] = s1; scorr[e] = s1 + gb[e];
    }
    float gs[4];
    for (int g = 0; g < 4; ++g) {
      float m1 = -1e30f, m2 = -1e30f;
      for (int j = 0; j < 4; ++j) {
        float v = scorr[g * 4 + j];
        if (v > m1) { m2 = m1; m1 = v; } else if (v > m2) m2 = v;
      }
      gs[g] = m1 + m2;
    }
    int g1 = 0;
    for (int g = 1; g < 4; ++g) if (gs[g] > gs[g1]) g1 = g;
    int g2 = -1;
    for (int g = 0; g < 4; ++g) { if (g == g1) continue; if (g2 < 0 || gs[g] > gs[g2]) g2 = g; }

    bool taken[NEXP];
    for (int e = 0; e < NEXP; ++e) taken[e] = false;
    int ids[TOPK]; float wv[TOPK]; float wsum = 0.f;
    for (int k = 0; k < TOPK; ++k) {
      int best = -1; float bv = -1e30f;
      for (int e = 0; e < NEXP; ++e) {
        int grp = e >> 2;
        if (grp != g1 && grp != g2) continue;
        if (taken[e]) continue;
        if (scorr[e] > bv) { bv = scorr[e]; best = e; }
      }
      taken[best] = true; ids[k] = best; wv[k] = sc[best]; wsum += sc[best];
    }
    float inv = 2.5f / wsum;
    for (int k = 0; k < TOPK; ++k) {
      int e = ids[k];
      int slot = atomicAdd(&counts[e], 1);
      tok_list[e * CAP + slot] = t;
      pw[e * CAP + slot] = wv[k] * inv;
    }
  }
}

// ----------------------------------------------- weight convert+transpose ---
// f32 W[z][K][N]  ->  bf16 Wt[z][N][K].  64x64 LDS tiles, coalesced both sides.
__global__ __launch_bounds__(256) void transpose_bf16_k(
    const float* __restrict__ W, unsigned short* __restrict__ Wt, int K, int N)
{
  const size_t base = (size_t)blockIdx.z * (size_t)K * N;
  const int k0 = blockIdx.y * 64, n0 = blockIdx.x * 64;
  __shared__ unsigned short t[64][65];
  const int tid = threadIdx.x;
  #pragma unroll
  for (int i = 0; i < 4; ++i) {
    int c = tid + 256 * i;                 // 1024 float4 chunks
    int kk = c >> 4, nn = (c & 15) * 4;
    float4 f = *(const float4*)(W + base + (size_t)(k0 + kk) * N + (n0 + nn));
    t[kk][nn + 0] = f2bf(f.x); t[kk][nn + 1] = f2bf(f.y);
    t[kk][nn + 2] = f2bf(f.z); t[kk][nn + 3] = f2bf(f.w);
  }
  __syncthreads();
  #pragma unroll
  for (int i = 0; i < 2; ++i) {
    int c = tid + 256 * i;                 // 512 chunks of 8 k
    int nl = c >> 3, kq = (c & 7) * 8;
    unsigned out4[4];
    #pragma unroll
    for (int j = 0; j < 4; ++j) {
      unsigned lo = t[kq + 2 * j][nl], hv = t[kq + 2 * j + 1][nl];
      out4[j] = lo | (hv << 16);
    }
    *(uint4*)(Wt + base + (size_t)(n0 + nl) * K + (k0 + kq)) = *(uint4*)out4;
  }
}

// --------------------------------------------------- bf16 GEMM (main path) --
// 128x128 tile, BK=64, 4 waves (2x2), A and B both bf16 [row][K] row-major.
// global_load_lds width=16 with inverse-swizzled source; ds_read_b128 with
// (r&7)<<4 XOR swizzle.  MODE 0: swiglu->bf16 act (BN=64 g-cols + 64 u-cols).
// MODE 1: y*pw atomic scatter (BN=128).  MODE 2: plain f32 store (BN=128).
template<int MODE>
__global__ __launch_bounds__(256) void gemm_bf16_k(
    const unsigned short* __restrict__ A, int lda, size_t a_estride,
    const unsigned short* __restrict__ Wt, int K, size_t w_estride, int u_off,
    const int* __restrict__ counts, int M_direct,
    const int* __restrict__ tok_list,
    unsigned short* __restrict__ act_out, int act_ld, size_t act_estride,
    const float* __restrict__ pw, float* __restrict__ out)
{
  const int e  = blockIdx.z;
  const int m0 = blockIdx.y * 128;
  const int M  = counts ? counts[e] : M_direct;
  if (m0 >= M) return;
  const int n0 = blockIdx.x * (MODE == 0 ? 64 : 128);

  __shared__ __align__(16) unsigned short Al[128 * 64];   // 16 KB
  __shared__ __align__(16) unsigned short Bl[128 * 64];   // 16 KB

  const int tid = threadIdx.x, lane = tid & 63, wid = tid >> 6;
  const int wm = wid >> 1, wn = wid & 1, l15 = lane & 15, hi = lane >> 4;

  const unsigned short* Ap = A + (size_t)e * a_estride;
  const unsigned short* Wp = Wt + (size_t)e * w_estride;

  // staging descriptors (constant over K-loop)
  const unsigned short* asrc[4]; void* adst[4];
  const unsigned short* bsrc[4]; void* bdst[4];
  #pragma unroll
  for (int i = 0; i < 4; ++i) {
    int c = tid + 256 * i;                 // 0..1023, 16B each
    int r = c >> 3, s = c & 7, sl = s ^ (r & 7);
    // ---- A row ----
    int slot = m0 + r;
    int row = slot;
    if (MODE == 0 && tok_list) row = (slot < M) ? tok_list[e * CAP + slot] : 0;
    asrc[i] = Ap + (size_t)row * lda + sl * 8;
    adst[i] = (char*)Al + c * 16;
    // ---- B row ----
    int nrow;
    if (MODE == 0) nrow = (r < 64) ? (n0 + r) : (u_off + n0 + r - 64);
    else           nrow = n0 + r;
    bsrc[i] = Wp + (size_t)nrow * K + sl * 8;
    bdst[i] = (char*)Bl + c * 16;
  }

  int bn[4];
  if (MODE == 0) { bn[0] = wn*32; bn[1] = wn*32+16; bn[2] = 64+wn*32; bn[3] = 80+wn*32; }
  else           { bn[0] = wn*64; bn[1] = wn*64+16; bn[2] = wn*64+32; bn[3] = wn*64+48; }

  f32x4 acc[4][4];
  #pragma unroll
  for (int a0 = 0; a0 < 4; ++a0)
    #pragma unroll
    for (int b0 = 0; b0 < 4; ++b0) acc[a0][b0] = (f32x4){0.f, 0.f, 0.f, 0.f};

  for (int kt = 0; kt < K; kt += 64) {
    #pragma unroll
    for (int i = 0; i < 4; ++i) gll16(asrc[i] + kt, adst[i]);
    #pragma unroll
    for (int i = 0; i < 4; ++i) gll16(bsrc[i] + kt, bdst[i]);
    __syncthreads();

    #pragma unroll
    for (int kk = 0; kk < 64; kk += 32) {
      bf16x8 af[4], bv[4];
      #pragma unroll
      for (int mi = 0; mi < 4; ++mi) {
        int r = wm * 64 + mi * 16 + l15;
        int off = (r * 128 + (kk + hi * 8) * 2) ^ ((r & 7) << 4);
        af[mi] = *(const bf16x8*)((const char*)Al + off);
      }
      #pragma unroll
      for (int ni = 0; ni < 4; ++ni) {
        int r = bn[ni] + l15;
        int off = (r * 128 + (kk + hi * 8) * 2) ^ ((r & 7) << 4);
        bv[ni] = *(const bf16x8*)((const char*)Bl + off);
      }
      #pragma unroll
      for (int mi = 0; mi < 4; ++mi)
        #pragma unroll
        for (int ni = 0; ni < 4; ++ni)
          acc[mi][ni] = __builtin_amdgcn_mfma_f32_16x16x32_bf16(af[mi], bv[ni], acc[mi][ni], 0, 0, 0);
    }
    __syncthreads();
  }

  // ---- epilogue ----  C/D: col=lane&15, row=(lane>>4)*4+reg
  const int rbase = hi * 4;
  if (MODE == 0) {
    #pragma unroll
    for (int mi = 0; mi < 4; ++mi)
      #pragma unroll
      for (int rr = 0; rr < 4; ++rr) {
        int slot = m0 + wm * 64 + mi * 16 + rbase + rr;
        if (slot >= M) continue;
        #pragma unroll
        for (int j = 0; j < 2; ++j) {
          float g = acc[mi][j][rr], u = acc[mi][j + 2][rr];
          float sv = g / (1.f + expf(-g)) * u;
          int col = n0 + wn * 32 + j * 16 + l15;
          act_out[(size_t)e * act_estride + (size_t)slot * act_ld + col] = f2bf(sv);
        }
      }
  } else if (MODE == 1) {
    #pragma unroll
    for (int mi = 0; mi < 4; ++mi)
      #pragma unroll
      for (int rr = 0; rr < 4; ++rr) {
        int slot = m0 + wm * 64 + mi * 16 + rbase + rr;
        if (slot >= M) continue;
        int tokn = tok_list[e * CAP + slot];
        float wvv = pw[e * CAP + slot];
        float* orow = out + (size_t)tokn * HID + n0;
        #pragma unroll
        for (int ni = 0; ni < 4; ++ni)
          atomicAdd(orow + bn[ni] + l15, acc[mi][ni][rr] * wvv);
      }
  } else {
    #pragma unroll
    for (int mi = 0; mi < 4; ++mi)
      #pragma unroll
      for (int rr = 0; rr < 4; ++rr) {
        int rowg = m0 + wm * 64 + mi * 16 + rbase + rr;
        #pragma unroll
        for (int ni = 0; ni < 4; ++ni)
          out[(size_t)rowg * HID + n0 + bn[ni] + l15] = acc[mi][ni][rr];
      }
  }
}

// ------------------------------------------- fallback f32-direct GEMM -------
// (round-1 kernel, verbatim; used only if ws_size is too small)
template<int MODE>
__global__ __launch_bounds__(256) void gemm_k(
    const unsigned short* __restrict__ A, int lda, size_t a_estride,
    const float* __restrict__ W, int K, int Nfull, size_t w_estride,
    const int* __restrict__ counts, int M_direct,
    const int* __restrict__ tok_list,
    unsigned short* __restrict__ act_out, int act_ld, size_t act_estride, int u_off,
    const float* __restrict__ pw, float* __restrict__ out, int out_ld)
{
  const int e  = blockIdx.z;
  const int m0 = blockIdx.y * 64;
  const int M  = counts ? counts[e] : M_direct;
  if (m0 >= M) return;
  const int BN = (MODE == 0) ? 64 : 128;
  const int n0 = blockIdx.x * BN;

  __shared__ __align__(16) unsigned short Al[64 * 64];
  __shared__ __align__(16) unsigned short Bl[128 * 64];

  const int tid  = threadIdx.x;
  const int lane = tid & 63;
  const int wid  = tid >> 6;
  const int wm = wid >> 1, wn = wid & 1;
  const int l15 = lane & 15;

  const float* Wp = W + (size_t)e * w_estride;
  const unsigned short* Ap = A + (size_t)e * a_estride;

  const unsigned short* aptr[2]; int aoff[2];
  #pragma unroll
  for (int i = 0; i < 2; ++i) {
    int c = tid + 256 * i;
    int r = c >> 3, col = (c & 7) * 8;
    int slot = m0 + r;
    const unsigned short* p = nullptr;
    if (slot < M) {
      int row_idx = (MODE == 0 && tok_list) ? tok_list[e * CAP + slot] : slot;
      p = Ap + (size_t)row_idx * lda + col;
    }
    aptr[i] = p;
    aoff[i] = (r * 128 + col * 2) ^ ((r & 7) << 4);
  }
  int bk_[8], bnl_[8]; size_t bgoff[8];
  #pragma unroll
  for (int i = 0; i < 8; ++i) {
    int c = tid + 256 * i;
    int k = c >> 5, nl = (c & 31) * 4;
    bk_[i] = k; bnl_[i] = nl;
    int ng;
    if (MODE == 0) ng = (nl < 64) ? (n0 + nl) : (u_off + n0 + nl - 64);
    else           ng = n0 + nl;
    bgoff[i] = (size_t)k * Nfull + ng;
  }

  int bn[4];
  if (MODE == 0) { bn[0] = wn*32; bn[1] = wn*32+16; bn[2] = 64+wn*32; bn[3] = 80+wn*32; }
  else           { bn[0] = wn*64; bn[1] = wn*64+16; bn[2] = wn*64+32; bn[3] = wn*64+48; }

  f32x4 acc[2][4];
  #pragma unroll
  for (int a0 = 0; a0 < 2; ++a0)
    #pragma unroll
    for (int b0 = 0; b0 < 4; ++b0) acc[a0][b0] = (f32x4){0.f, 0.f, 0.f, 0.f};

  for (int kt = 0; kt < K; kt += 64) {
    #pragma unroll
    for (int i = 0; i < 2; ++i) {
      uint4 v = {0u, 0u, 0u, 0u};
      if (aptr[i]) v = *(const uint4*)(aptr[i] + kt);
      *(uint4*)((char*)Al + aoff[i]) = v;
    }
    #pragma unroll
    for (int i = 0; i < 8; ++i) {
      float4 f = *(const float4*)(Wp + (size_t)kt * Nfull + bgoff[i]);
      unsigned short h[4] = { f2bf(f.x), f2bf(f.y), f2bf(f.z), f2bf(f.w) };
      #pragma unroll
      for (int j = 0; j < 4; ++j) {
        int r2 = bnl_[i] + j;
        int off = (r2 * 128 + bk_[i] * 2) ^ ((r2 & 7) << 4);
        *(unsigned short*)((char*)Bl + off) = h[j];
      }
    }
    __syncthreads();

    #pragma unroll
    for (int kk = 0; kk < 64; kk += 32) {
      bf16x8 af[2], bfv[4];
      #pragma unroll
      for (int mi = 0; mi < 2; ++mi) {
        int r = wm * 32 + mi * 16 + l15;
        int off = (r * 128 + (kk + ((lane >> 4) << 3)) * 2) ^ ((r & 7) << 4);
        af[mi] = *(const bf16x8*)((const char*)Al + off);
      }
      #pragma unroll
      for (int bj = 0; bj < 4; ++bj) {
        int r = bn[bj] + l15;
        int off = (r * 128 + (kk + ((lane >> 4) << 3)) * 2) ^ ((r & 7) << 4);
        bfv[bj] = *(const bf16x8*)((const char*)Bl + off);
      }
      #pragma unroll
      for (int mi = 0; mi < 2; ++mi)
        #pragma unroll
        for (int bj = 0; bj < 4; ++bj)
          acc[mi][bj] = __builtin_amdgcn_mfma_f32_16x16x32_bf16(af[mi], bfv[bj], acc[mi][bj], 0, 0, 0);
    }
    __syncthreads();
  }

  const int rowin = (lane >> 4) * 4;
  if (MODE == 0) {
    #pragma unroll
    for (int mi = 0; mi < 2; ++mi)
      #pragma unroll
      for (int r = 0; r < 4; ++r) {
        int slot = m0 + wm * 32 + mi * 16 + rowin + r;
        if (slot >= M) continue;
        #pragma unroll
        for (int bjh = 0; bjh < 2; ++bjh) {
          float g = acc[mi][bjh][r];
          float u = acc[mi][bjh + 2][r];
          float sv = g / (1.f + expf(-g)) * u;
          int colc = n0 + bn[bjh] + l15;
          act_out[(size_t)e * act_estride + (size_t)slot * act_ld + colc] = f2bf(sv);
        }
      }
  } else if (MODE == 1) {
    #pragma unroll
    for (int mi = 0; mi < 2; ++mi)
      #pragma unroll
      for (int r = 0; r < 4; ++r) {
        int slot = m0 + wm * 32 + mi * 16 + rowin + r;
        if (slot >= M) continue;
        int tokn = tok_list[e * CAP + slot];
        float wvv = pw[e * CAP + slot];
        float* orow = out + (size_t)tokn * out_ld;
        #pragma unroll
        for (int bj = 0; bj < 4; ++bj)
          atomicAdd(orow + (n0 + bn[bj] + l15), acc[mi][bj][r] * wvv);
      }
  } else {
    #pragma unroll
    for (int mi = 0; mi < 2; ++mi)
      #pragma unroll
      for (int r = 0; r < 4; ++r) {
        int rowg = m0 + wm * 32 + mi * 16 + rowin + r;
        #pragma unroll
        for (int bj = 0; bj < 4; ++bj)
          out[(size_t)rowg * out_ld + (n0 + bn[bj] + l15)] = acc[mi][bj][r];
      }
  }
}

// --------------------------------------------------------------- launcher ---
extern "C" void kernel_launch(void* const* d_in, const int* in_sizes, int n_in,
                              void* d_out, int out_size, void* d_ws, size_t ws_size,
                              hipStream_t stream) {
  const float* x   = (const float*)d_in[0];
  const float* gw  = (const float*)d_in[1];
  const float* gb  = (const float*)d_in[2];
  const float* wgu = (const float*)d_in[3];
  const float* wd  = (const float*)d_in[4];
  const float* sgu = (const float*)d_in[5];
  const float* sd  = (const float*)d_in[6];
  float* out = (float*)d_out;

  char* ws = (char*)d_ws;
  int*   counts   = (int*)ws;                                   // 256 B
  int*   tok_list = (int*)(ws + 256);                           // 64 KB
  float* pw       = (float*)(ws + 256 + (size_t)64 * 1024);     // 64 KB
  unsigned short* x_bf   = (unsigned short*)(ws + 256 + (size_t)128 * 1024);
  unsigned short* act_e  = x_bf + (size_t)N_TOK * HID;          // 32 MiB
  unsigned short* act_sh = act_e + (size_t)NEXP * CAP * INTER;  // 4 MiB
  unsigned short* wgu_t  = act_sh + (size_t)N_TOK * HID;        // 128 MiB
  unsigned short* wd_t   = wgu_t + (size_t)NEXP * HID * 2 * INTER;  // 64 MiB
  unsigned short* sgu_t  = wd_t + (size_t)NEXP * INTER * HID;   // 16 MiB
  unsigned short* sd_t   = sgu_t + (size_t)HID * 4096;          // 8 MiB
  const size_t need = (size_t)((char*)(sd_t + (size_t)HID * HID) - ws);

  hipMemsetAsync(counts, 0, 256, stream);
  router_k<<<N_TOK, 256, 0, stream>>>(x, gw, gb, counts, tok_list, pw, x_bf);

  if (ws_size >= need) {
    // ---- convert + transpose all weights to bf16 [n][k] ----
    transpose_bf16_k<<<dim3(HID / 64, HID / 64, NEXP), 256, 0, stream>>>(wgu, wgu_t, HID, 2 * INTER);
    transpose_bf16_k<<<dim3(HID / 64, INTER / 64, NEXP), 256, 0, stream>>>(wd, wd_t, INTER, HID);
    transpose_bf16_k<<<dim3(4096 / 64, HID / 64, 1), 256, 0, stream>>>(sgu, sgu_t, HID, 4096);
    transpose_bf16_k<<<dim3(HID / 64, HID / 64, 1), 256, 0, stream>>>(sd, sd_t, HID, HID);

    // shared gemm1: x @ sgu, swiglu -> act_sh[1024][2048]
    gemm_bf16_k<0><<<dim3(2048 / 64, N_TOK / 128, 1), 256, 0, stream>>>(
        x_bf, HID, 0, sgu_t, HID, 0, 2048, nullptr, N_TOK, nullptr,
        act_sh, 2048, 0, nullptr, nullptr);
    // expert gemm1: gather(x) @ wgu[e], swiglu -> act_e[e][*][1024]
    gemm_bf16_k<0><<<dim3(INTER / 64, CAP / 128, NEXP), 256, 0, stream>>>(
        x_bf, HID, 0, wgu_t, HID, (size_t)2 * INTER * HID, INTER, counts, 0, tok_list,
        act_e, INTER, (size_t)CAP * INTER, nullptr, nullptr);
    // shared gemm2: act_sh @ sd -> out (plain store, initializes d_out)
    gemm_bf16_k<2><<<dim3(HID / 128, N_TOK / 128, 1), 256, 0, stream>>>(
        act_sh, 2048, 0, sd_t, HID, 0, 0, nullptr, N_TOK, nullptr,
        nullptr, 0, 0, nullptr, out);
    // expert gemm2: act_e[e] @ wd[e] * pw -> atomicAdd(out)
    gemm_bf16_k<1><<<dim3(HID / 128, CAP / 128, NEXP), 256, 0, stream>>>(
        act_e, INTER, (size_t)CAP * INTER, wd_t, INTER, (size_t)INTER * HID, 0, counts, 0, tok_list,
        nullptr, 0, 0, pw, out);
  } else {
    // ---- fallback: direct f32-weight GEMMs (round-1 path) ----
    gemm_k<0><<<dim3(32, 16, 1), 256, 0, stream>>>(
        x_bf, HID, 0, sgu, HID, 4096, 0, nullptr, N_TOK, nullptr,
        act_sh, 2048, 0, 2048, nullptr, nullptr, 0);
    gemm_k<0><<<dim3(16, 16, 16), 256, 0, stream>>>(
        x_bf, HID, 0, wgu, HID, 2 * INTER, (size_t)HID * 2 * INTER, counts, 0, tok_list,
        act_e, INTER, (size_t)CAP * INTER, INTER, nullptr, nullptr, 0);
    gemm_k<2><<<dim3(16, 16, 1), 256, 0, stream>>>(
        act_sh, 2048, 0, sd, 2048, HID, 0, nullptr, N_TOK, nullptr,
        nullptr, 0, 0, 0, nullptr, out, HID);
    gemm_k<1><<<dim3(16, 16, 16), 256, 0, stream>>>(
        act_e, INTER, (size_t)CAP * INTER, wd, INTER, HID, (size_t)INTER * HID, counts, 0, tok_list,
        nullptr, 0, 0, 0, pw, out, HID);
  }
}

// Round 3
// 430.422 us; speedup vs baseline: 2.8105x; 1.2358x over previous
//
#include <hip/hip_runtime.h>
#include <hip/hip_bf16.h>
#include <math.h>

typedef __attribute__((ext_vector_type(8))) short bf16x8;
typedef __attribute__((ext_vector_type(4))) float f32x4;

#define N_TOK 1024
#define HID   2048
#define NEXP  16
#define NE2   18      // 16 routed + 2 shared pseudo-experts
#define INTER 1024
#define TOPK  6
#define CAP   1024

__device__ __forceinline__ unsigned short f2bf(float f) {
  unsigned u = __builtin_bit_cast(unsigned, f);
  u += 0x7fffu + ((u >> 16) & 1u);          // round-to-nearest-even
  return (unsigned short)(u >> 16);
}
__device__ __forceinline__ float b2f(short s) {
  unsigned u = ((unsigned)(unsigned short)s) << 16;
  return __builtin_bit_cast(float, u);
}
__device__ __forceinline__ void gll16(const void* g, void* l) {
  __builtin_amdgcn_global_load_lds(
      (const __attribute__((address_space(1))) unsigned int*)g,
      (__attribute__((address_space(3))) unsigned int*)l, 16, 0, 0);
}

// ---------------------------------------------------------------- router ----
// One block per token: logits, sigmoid, grouped top-k, renorm*2.5.
// Emits: per-expert slot lists (for GEMM gather) AND per-token (e,slot,w)
// metadata (for the gather-combine). Also x -> bf16.
__global__ __launch_bounds__(256) void router_k(
    const float* __restrict__ x, const float* __restrict__ gw,
    const float* __restrict__ gb, int* __restrict__ counts,
    int* __restrict__ tok_list, int* __restrict__ meta,
    float* __restrict__ pwt, unsigned short* __restrict__ x_bf)
{
  const int t   = blockIdx.x;
  const int tid = threadIdx.x;
  __shared__ float xrow[HID];
  __shared__ float logits[NEXP];

  for (int i = tid; i < HID; i += 256) {
    float v = x[(size_t)t * HID + i];
    xrow[i] = v;
    x_bf[(size_t)t * HID + i] = f2bf(v);
  }
  __syncthreads();

  const int w = tid >> 6, lane = tid & 63;
  for (int s = 0; s < 4; ++s) {
    int e = w * 4 + s;
    const float* g = gw + (size_t)e * HID;
    float p = 0.f;
    for (int i = lane; i < HID; i += 64) p += xrow[i] * g[i];
    for (int off = 32; off; off >>= 1) p += __shfl_down(p, off);
    if (lane == 0) logits[e] = p;
  }
  __syncthreads();

  if (tid == 0) {
    float sc[NEXP], scorr[NEXP];
    for (int e = 0; e < NEXP; ++e) {
      float s1 = 1.f / (1.f + expf(-logits[e]));
      sc[e] = s1; scorr[e] = s1 + gb[e];
    }
    float gs[4];
    for (int g = 0; g < 4; ++g) {
      float m1 = -1e30f, m2 = -1e30f;
      for (int j = 0; j < 4; ++j) {
        float v = scorr[g * 4 + j];
        if (v > m1) { m2 = m1; m1 = v; } else if (v > m2) m2 = v;
      }
      gs[g] = m1 + m2;
    }
    int g1 = 0;
    for (int g = 1; g < 4; ++g) if (gs[g] > gs[g1]) g1 = g;
    int g2 = -1;
    for (int g = 0; g < 4; ++g) { if (g == g1) continue; if (g2 < 0 || gs[g] > gs[g2]) g2 = g; }

    bool taken[NEXP];
    for (int e = 0; e < NEXP; ++e) taken[e] = false;
    int ids[TOPK]; float wv[TOPK]; float wsum = 0.f;
    for (int k = 0; k < TOPK; ++k) {
      int best = -1; float bv = -1e30f;
      for (int e = 0; e < NEXP; ++e) {
        int grp = e >> 2;
        if (grp != g1 && grp != g2) continue;
        if (taken[e]) continue;
        if (scorr[e] > bv) { bv = scorr[e]; best = e; }
      }
      taken[best] = true; ids[k] = best; wv[k] = sc[best]; wsum += sc[best];
    }
    float inv = 2.5f / wsum;
    for (int k = 0; k < TOPK; ++k) {
      int e = ids[k];
      int slot = atomicAdd(&counts[e], 1);
      tok_list[e * CAP + slot] = t;
      meta[t * TOPK + k] = (e << 16) | slot;
      pwt[t * TOPK + k] = wv[k] * inv;
    }
  }
}

// ----------------------------------------------- weight convert+transpose ---
// wt_gu[z][n][k]: z<16 -> wgu[z][k][n] (g cols 0..1023, u cols 1024..2047,
// natural). z=16+j -> sgu[k][c], c = j*1024+n (g half) or 1024*j+1024+n (u).
__global__ __launch_bounds__(256) void t_gu_k(
    const float* __restrict__ wgu, const float* __restrict__ sgu,
    unsigned short* __restrict__ dst)
{
  const int z = blockIdx.z;
  const int n0 = blockIdx.x * 64, k0 = blockIdx.y * 64;
  const float* src; int ld; int cb;
  if (z < 16) { src = wgu + (size_t)z * HID * (2 * INTER); ld = 2 * INTER; cb = n0; }
  else { int j = z - 16; src = sgu; ld = 4096;
         cb = (n0 < 1024) ? j * 1024 + n0 : 1024 * j + 1024 + n0; }
  __shared__ unsigned short t[64][65];
  const int tid = threadIdx.x;
  #pragma unroll
  for (int i = 0; i < 4; ++i) {
    int c = tid + 256 * i;
    int kk = c >> 4, nn = (c & 15) * 4;
    float4 f = *(const float4*)(src + (size_t)(k0 + kk) * ld + cb + nn);
    t[kk][nn + 0] = f2bf(f.x); t[kk][nn + 1] = f2bf(f.y);
    t[kk][nn + 2] = f2bf(f.z); t[kk][nn + 3] = f2bf(f.w);
  }
  __syncthreads();
  unsigned short* d = dst + (size_t)z * HID * (2 * INTER);
  #pragma unroll
  for (int i = 0; i < 2; ++i) {
    int c = tid + 256 * i;
    int nl = c >> 3, kq = (c & 7) * 8;
    unsigned o4[4];
    #pragma unroll
    for (int j = 0; j < 4; ++j) {
      unsigned lo = t[kq + 2 * j][nl], hv = t[kq + 2 * j + 1][nl];
      o4[j] = lo | (hv << 16);
    }
    *(uint4*)(d + (size_t)(n0 + nl) * HID + k0 + kq) = *(uint4*)o4;
  }
}

// wt_d[z][n(2048)][k(1024)]: z<16 -> wd[z][k][n]; z=16+j -> sd[j*1024+k][n].
// (wd slices and sd halves have identical [1024][2048] layout.)
__global__ __launch_bounds__(256) void t_d_k(
    const float* __restrict__ wd, const float* __restrict__ sd,
    unsigned short* __restrict__ dst)
{
  const int z = blockIdx.z;
  const int n0 = blockIdx.x * 64, k0 = blockIdx.y * 64;
  const float* src = (z < 16) ? wd + (size_t)z * INTER * HID
                              : sd + (size_t)(z - 16) * INTER * HID;
  __shared__ unsigned short t[64][65];
  const int tid = threadIdx.x;
  #pragma unroll
  for (int i = 0; i < 4; ++i) {
    int c = tid + 256 * i;
    int kk = c >> 4, nn = (c & 15) * 4;
    float4 f = *(const float4*)(src + (size_t)(k0 + kk) * HID + n0 + nn);
    t[kk][nn + 0] = f2bf(f.x); t[kk][nn + 1] = f2bf(f.y);
    t[kk][nn + 2] = f2bf(f.z); t[kk][nn + 3] = f2bf(f.w);
  }
  __syncthreads();
  unsigned short* d = dst + (size_t)z * HID * INTER;
  #pragma unroll
  for (int i = 0; i < 2; ++i) {
    int c = tid + 256 * i;
    int nl = c >> 3, kq = (c & 7) * 8;
    unsigned o4[4];
    #pragma unroll
    for (int j = 0; j < 4; ++j) {
      unsigned lo = t[kq + 2 * j][nl], hv = t[kq + 2 * j + 1][nl];
      o4[j] = lo | (hv << 16);
    }
    *(uint4*)(d + (size_t)(n0 + nl) * INTER + k0 + kq) = *(uint4*)o4;
  }
}

// --------------------------------------------------- grouped bf16 GEMM ------
// 128x128 tile, BK=64, 4 waves (2x2). A,B bf16 row-major along K.
// global_load_lds w=16, linear LDS dest + inverse-swizzled source; ds_read_b128
// with (r&7)<<4 XOR swizzle (T2, both-sides).
// MODE 0: gemm1 — gather A rows via tok_list (e<16) or identity (shared);
//         B rows r<64 = g (n0+r), r>=64 = u (1024+n0+r-64); swiglu -> bf16 act.
// MODE 1: gemm2 — A rows = slots; plain bf16 store to y_buf.
template<int MODE>
__global__ __launch_bounds__(256) void gemm_bf16_k(
    const unsigned short* __restrict__ A, int lda, size_t a_estride,
    const unsigned short* __restrict__ Wt, int K, size_t w_estride,
    const int* __restrict__ counts, const int* __restrict__ tok_list,
    unsigned short* __restrict__ outb, int out_ld, size_t out_estride)
{
  const int e  = blockIdx.z;
  const int m0 = blockIdx.y * 128;
  const int M  = (e < 16) ? counts[e] : N_TOK;
  if (m0 >= M) return;
  const int n0 = blockIdx.x * (MODE == 0 ? 64 : 128);

  __shared__ __align__(16) unsigned short Al[128 * 64];   // 16 KB
  __shared__ __align__(16) unsigned short Bl[128 * 64];   // 16 KB

  const int tid = threadIdx.x, lane = tid & 63, wid = tid >> 6;
  const int wm = wid >> 1, wn = wid & 1, l15 = lane & 15, hi = lane >> 4;

  const unsigned short* Ap = A + (size_t)e * a_estride;
  const unsigned short* Wp = Wt + (size_t)e * w_estride;

  const unsigned short* asrc[4]; void* adst[4];
  const unsigned short* bsrc[4]; void* bdst[4];
  #pragma unroll
  for (int i = 0; i < 4; ++i) {
    int c = tid + 256 * i;                 // 0..1023, 16B each
    int r = c >> 3, s = c & 7, sl = s ^ (r & 7);
    int slot = m0 + r;
    int row;
    if (MODE == 0) row = (e < 16) ? ((slot < M) ? tok_list[e * CAP + slot] : 0) : slot;
    else           row = slot;
    asrc[i] = Ap + (size_t)row * lda + sl * 8;
    adst[i] = (char*)Al + c * 16;
    int nrow = (MODE == 0) ? ((r < 64) ? n0 + r : 1024 + n0 + (r - 64)) : (n0 + r);
    bsrc[i] = Wp + (size_t)nrow * K + sl * 8;
    bdst[i] = (char*)Bl + c * 16;
  }

  int bn[4];
  if (MODE == 0) { bn[0] = wn*32; bn[1] = wn*32+16; bn[2] = 64+wn*32; bn[3] = 80+wn*32; }
  else           { bn[0] = wn*64; bn[1] = wn*64+16; bn[2] = wn*64+32; bn[3] = wn*64+48; }

  f32x4 acc[4][4];
  #pragma unroll
  for (int a0 = 0; a0 < 4; ++a0)
    #pragma unroll
    for (int b0 = 0; b0 < 4; ++b0) acc[a0][b0] = (f32x4){0.f, 0.f, 0.f, 0.f};

  for (int kt = 0; kt < K; kt += 64) {
    #pragma unroll
    for (int i = 0; i < 4; ++i) gll16(asrc[i] + kt, adst[i]);
    #pragma unroll
    for (int i = 0; i < 4; ++i) gll16(bsrc[i] + kt, bdst[i]);
    __syncthreads();

    #pragma unroll
    for (int kk = 0; kk < 64; kk += 32) {
      bf16x8 af[4], bv[4];
      #pragma unroll
      for (int mi = 0; mi < 4; ++mi) {
        int r = wm * 64 + mi * 16 + l15;
        int off = (r * 128 + (kk + hi * 8) * 2) ^ ((r & 7) << 4);
        af[mi] = *(const bf16x8*)((const char*)Al + off);
      }
      #pragma unroll
      for (int ni = 0; ni < 4; ++ni) {
        int r = bn[ni] + l15;
        int off = (r * 128 + (kk + hi * 8) * 2) ^ ((r & 7) << 4);
        bv[ni] = *(const bf16x8*)((const char*)Bl + off);
      }
      #pragma unroll
      for (int mi = 0; mi < 4; ++mi)
        #pragma unroll
        for (int ni = 0; ni < 4; ++ni)
          acc[mi][ni] = __builtin_amdgcn_mfma_f32_16x16x32_bf16(af[mi], bv[ni], acc[mi][ni], 0, 0, 0);
    }
    __syncthreads();
  }

  // ---- epilogue ----  C/D: col=lane&15, row=(lane>>4)*4+reg
  const int rbase = hi * 4;
  if (MODE == 0) {
    #pragma unroll
    for (int mi = 0; mi < 4; ++mi)
      #pragma unroll
      for (int rr = 0; rr < 4; ++rr) {
        int slot = m0 + wm * 64 + mi * 16 + rbase + rr;
        if (slot >= M) continue;
        #pragma unroll
        for (int j = 0; j < 2; ++j) {
          float g = acc[mi][j][rr], u = acc[mi][j + 2][rr];
          float sv = g / (1.f + expf(-g)) * u;
          int col = n0 + wn * 32 + j * 16 + l15;
          outb[(size_t)e * out_estride + (size_t)slot * out_ld + col] = f2bf(sv);
        }
      }
  } else {
    #pragma unroll
    for (int mi = 0; mi < 4; ++mi)
      #pragma unroll
      for (int rr = 0; rr < 4; ++rr) {
        int slot = m0 + wm * 64 + mi * 16 + rbase + rr;
        if (slot >= M) continue;
        unsigned short* row = outb + (size_t)e * out_estride + (size_t)slot * out_ld;
        #pragma unroll
        for (int ni = 0; ni < 4; ++ni)
          row[n0 + bn[ni] + l15] = f2bf(acc[mi][ni][rr]);
      }
  }
}

// ---------------------------------------------------------------- combine ---
// out[t] = sum_k pw[t,k]*y[e_k][slot_k] + y[16][t] + y[17][t]
__global__ __launch_bounds__(256) void combine_k(
    const unsigned short* __restrict__ ybuf, const int* __restrict__ meta,
    const float* __restrict__ pwt, float* __restrict__ out)
{
  const int t = blockIdx.x;
  const int c0 = threadIdx.x * 8;
  float acc[8];
  {
    bf16x8 v0 = *(const bf16x8*)(ybuf + ((size_t)16 * CAP + t) * HID + c0);
    bf16x8 v1 = *(const bf16x8*)(ybuf + ((size_t)17 * CAP + t) * HID + c0);
    #pragma unroll
    for (int j = 0; j < 8; ++j) acc[j] = b2f(v0[j]) + b2f(v1[j]);
  }
  #pragma unroll
  for (int k = 0; k < TOPK; ++k) {
    int m = meta[t * TOPK + k];
    float w = pwt[t * TOPK + k];
    int e = m >> 16, s = m & 0xffff;
    bf16x8 v = *(const bf16x8*)(ybuf + ((size_t)e * CAP + s) * HID + c0);
    #pragma unroll
    for (int j = 0; j < 8; ++j) acc[j] += w * b2f(v[j]);
  }
  float4* o = (float4*)(out + (size_t)t * HID + c0);
  o[0] = make_float4(acc[0], acc[1], acc[2], acc[3]);
  o[1] = make_float4(acc[4], acc[5], acc[6], acc[7]);
}

// --------------------------------------------------------------- launcher ---
extern "C" void kernel_launch(void* const* d_in, const int* in_sizes, int n_in,
                              void* d_out, int out_size, void* d_ws, size_t ws_size,
                              hipStream_t stream) {
  const float* x   = (const float*)d_in[0];
  const float* gw  = (const float*)d_in[1];
  const float* gb  = (const float*)d_in[2];
  const float* wgu = (const float*)d_in[3];
  const float* wd  = (const float*)d_in[4];
  const float* sgu = (const float*)d_in[5];
  const float* sd  = (const float*)d_in[6];
  float* out = (float*)d_out;

  char* ws = (char*)d_ws;
  int*   counts   = (int*)ws;                              // 256 B
  int*   tok_list = (int*)(ws + 256);                      // 64 KB
  int*   meta     = (int*)(ws + 256 + 65536);              // 24 KB
  float* pwt      = (float*)(ws + 256 + 65536 + 24576);    // 24 KB
  unsigned short* x_bf  = (unsigned short*)(ws + 128 * 1024);          // 4 MiB
  unsigned short* act   = x_bf + (size_t)N_TOK * HID;                  // 36 MiB
  unsigned short* ybuf  = act + (size_t)NE2 * CAP * INTER;             // 72 MiB
  unsigned short* wt_gu = ybuf + (size_t)NE2 * CAP * HID;              // 144 MiB
  unsigned short* wt_d  = wt_gu + (size_t)NE2 * HID * 2 * INTER;       // 72 MiB
  const size_t need = (size_t)((char*)(wt_d + (size_t)NE2 * HID * INTER) - ws);
  if (ws_size < need) return;   // ws measured at 1 GiB; need ~328 MiB

  hipMemsetAsync(counts, 0, 256, stream);
  router_k<<<N_TOK, 256, 0, stream>>>(x, gw, gb, counts, tok_list, meta, pwt, x_bf);

  t_gu_k<<<dim3(2 * INTER / 64, HID / 64, NE2), 256, 0, stream>>>(wgu, sgu, wt_gu);
  t_d_k<<<dim3(HID / 64, INTER / 64, NE2), 256, 0, stream>>>(wd, sd, wt_d);

  // gemm1: [18] gather(x)[M,2048] @ wt_gu[e][n][k] -> swiglu -> act[e][M,1024]
  gemm_bf16_k<0><<<dim3(INTER / 64, CAP / 128, NE2), 256, 0, stream>>>(
      x_bf, HID, 0, wt_gu, HID, (size_t)HID * 2 * INTER, counts, tok_list,
      act, INTER, (size_t)CAP * INTER);
  // gemm2: [18] act[e][M,1024] @ wt_d[e][n][k] -> ybuf[e][M,2048] (bf16)
  gemm_bf16_k<1><<<dim3(HID / 128, CAP / 128, NE2), 256, 0, stream>>>(
      act, INTER, (size_t)CAP * INTER, wt_d, INTER, (size_t)HID * INTER, counts, nullptr,
      ybuf, HID, (size_t)CAP * HID);

  combine_k<<<N_TOK, 256, 0, stream>>>(ybuf, meta, pwt, out);
}